// Round 1
// baseline (271.806 us; speedup 1.0000x reference)
//
#include <hip/hip_runtime.h>
#include <math.h>

#define BN_EPS 1e-5f

// ---------------- Kernel 1: global average pool over H,W ----------------
// One block per (b,c) plane of 4096 floats.
__global__ __launch_bounds__(256) void pool_kernel(const float* __restrict__ x,
                                                   float* __restrict__ pooled) {
  int bc = blockIdx.x;                       // b*256 + c
  const float4* xp = reinterpret_cast<const float4*>(x + (size_t)bc * 4096);
  int tid = threadIdx.x;
  float s = 0.f;
#pragma unroll
  for (int k = 0; k < 4; ++k) {
    float4 v = xp[k * 256 + tid];
    s += (v.x + v.y) + (v.z + v.w);
  }
#pragma unroll
  for (int m = 32; m >= 1; m >>= 1) s += __shfl_xor(s, m, 64);
  __shared__ float wsum[4];
  if ((tid & 63) == 0) wsum[tid >> 6] = s;
  __syncthreads();
  if (tid == 0) pooled[bc] = (wsum[0] + wsum[1] + wsum[2] + wsum[3]) * (1.f / 4096.f);
}

// ---------------- Kernel 2: gate MLP (256 -> 64 relu -> 256 sigmoid) ----
// One block per batch element b.
__global__ __launch_bounds__(256) void gate_kernel(const float* __restrict__ pooled,
                                                   const float* __restrict__ fc1_w,
                                                   const float* __restrict__ fc1_b,
                                                   const float* __restrict__ fc2_w,
                                                   const float* __restrict__ fc2_b,
                                                   float* __restrict__ gate) {
  int b = blockIdx.x;
  int tid = threadIdx.x;
  __shared__ float p[256];
  __shared__ float hbuf[64];
  p[tid] = pooled[b * 256 + tid];
  __syncthreads();
  if (tid < 64) {
    float a = fc1_b[tid];
    const float* wr = fc1_w + tid * 256;
#pragma unroll 8
    for (int c = 0; c < 256; ++c) a += p[c] * wr[c];
    hbuf[tid] = fmaxf(a, 0.f);
  }
  __syncthreads();
  float g = fc2_b[tid];
  const float* w2 = fc2_w + tid * 64;
#pragma unroll 8
  for (int j = 0; j < 64; ++j) g += hbuf[j] * w2[j];
  gate[b * 256 + tid] = 1.f / (1.f + expf(-g));
}

// ---------------- Kernel 3: fused fc3 + reparam convs + BN + merge + gate
// Grid: (b, hpi, cgh) -> 2048 blocks. Wave = s (4 waves). Lane = (wpi, cgL).
// Each lane owns one 8x8 partition tile (registers) and produces 64 outputs.
__global__ __launch_bounds__(256) void main_kernel(
    const float* __restrict__ x, const float* __restrict__ fc3_w,
    const float* __restrict__ g3, const float* __restrict__ b3,
    const float* __restrict__ m3, const float* __restrict__ v3,
    const float* __restrict__ c1w,
    const float* __restrict__ g1, const float* __restrict__ b1,
    const float* __restrict__ m1, const float* __restrict__ v1,
    const float* __restrict__ c3w,
    const float* __restrict__ gk, const float* __restrict__ bk,
    const float* __restrict__ mk, const float* __restrict__ vk,
    const float* __restrict__ gate, float* __restrict__ out) {
  __shared__ float convbuf[256 * 64];  // per-thread 64-float conv results (XOR-rotated)
  int bid = blockIdx.x;
  int cgh = bid & 7;
  int hpi = (bid >> 3) & 7;
  int b   = bid >> 6;
  int tid = threadIdx.x;
  int s = __builtin_amdgcn_readfirstlane(tid >> 6);  // wave-uniform shareset
  int lane = tid & 63;
  int wpi = lane >> 3;
  int cgL = lane & 7;
  int c_in  = (cgh * 8 + cgL) * 4 + s;
  int c_out = hpi * 32 + wpi * 4 + s;

  // Load this lane's 8x8 tile into registers (wave covers 8 channels x full rows).
  float t[64];
  const float* xp = x + (((size_t)b * 256 + c_in) * 64 + (size_t)hpi * 8) * 64 + wpi * 8;
#pragma unroll
  for (int hh = 0; hh < 8; ++hh) {
    float4 va = *reinterpret_cast<const float4*>(xp + hh * 64);
    float4 vb = *reinterpret_cast<const float4*>(xp + hh * 64 + 4);
    t[hh * 8 + 0] = va.x; t[hh * 8 + 1] = va.y; t[hh * 8 + 2] = va.z; t[hh * 8 + 3] = va.w;
    t[hh * 8 + 4] = vb.x; t[hh * 8 + 5] = vb.y; t[hh * 8 + 6] = vb.z; t[hh * 8 + 7] = vb.w;
  }

  // Fold BN affine terms (all wave-uniform scalars).
  float sc3   = g3[s] * rsqrtf(v3[s] + BN_EPS);
  float bias3 = b3[s] - m3[s] * sc3;
  float sc1   = g1[s] * rsqrtf(v1[s] + BN_EPS);
  float bias1 = b1[s] - m1[s] * sc1;
  float sck   = gk[s] * rsqrtf(vk[s] + BN_EPS);
  float biask = bk[s] - mk[s] * sck;
  float cw[9];
#pragma unroll
  for (int d = 0; d < 9; ++d) cw[d] = sck * c3w[s * 9 + d];
  float c0   = sc1 * c1w[s] + cw[4];     // merged center tap (conv1 + conv3 center)
  float totb = bias3 + bias1 + biask;    // merged additive bias

  // Static conv pass (3x3 zero-padded within tile) -> LDS buffer.
  float* cb = &convbuf[tid * 64];
#pragma unroll
  for (int hh = 0; hh < 8; ++hh)
#pragma unroll
    for (int ww = 0; ww < 8; ++ww) {
      int o = hh * 8 + ww;
      float v = c0 * t[o];
#pragma unroll
      for (int dy = -1; dy <= 1; ++dy)
#pragma unroll
        for (int dx = -1; dx <= 1; ++dx) {
          if (dy == 0 && dx == 0) continue;
          int yy = hh + dy, xx = ww + dx;
          if (yy >= 0 && yy < 8 && xx >= 0 && xx < 8)
            v += cw[(dy + 1) * 3 + (dx + 1)] * t[yy * 8 + xx];
        }
      cb[(o + tid) & 63] = v;  // XOR/rotate index: 2 lanes/bank -> conflict-free
    }

  float gmul = gate[b * 256 + c_out];
  const float* wbase = fc3_w + s * 4096;                 // wave-uniform weight base
  float* outp = out + (((size_t)b * 256 + c_out) * 64 + (size_t)cgh * 8) * 64 + cgL * 8;

  for (int hh = 0; hh < 8; ++hh) {       // dynamic loop (small code, uniform addrs)
    float r0[8];
#pragma unroll
    for (int ww = 0; ww < 8; ++ww) {
      const float4* wr4 = reinterpret_cast<const float4*>(wbase + (hh * 8 + ww) * 64);
      float a0 = 0.f, a1 = 0.f, a2 = 0.f, a3 = 0.f;
#pragma unroll
      for (int i4 = 0; i4 < 16; ++i4) {
        float4 w4 = wr4[i4];
        a0 += t[i4 * 4 + 0] * w4.x;
        a1 += t[i4 * 4 + 1] * w4.y;
        a2 += t[i4 * 4 + 2] * w4.z;
        a3 += t[i4 * 4 + 3] * w4.w;
      }
      int o = hh * 8 + ww;
      float cv = cb[(o + tid) & 63];
      r0[ww] = (sc3 * ((a0 + a1) + (a2 + a3)) + cv + totb) * gmul;
    }
    *reinterpret_cast<float4*>(outp + hh * 64)     = make_float4(r0[0], r0[1], r0[2], r0[3]);
    *reinterpret_cast<float4*>(outp + hh * 64 + 4) = make_float4(r0[4], r0[5], r0[6], r0[7]);
  }
}

extern "C" void kernel_launch(void* const* d_in, const int* in_sizes, int n_in,
                              void* d_out, int out_size, void* d_ws, size_t ws_size,
                              hipStream_t stream) {
  const float* x     = (const float*)d_in[0];
  const float* fc1_w = (const float*)d_in[1];
  const float* fc1_b = (const float*)d_in[2];
  const float* fc2_w = (const float*)d_in[3];
  const float* fc2_b = (const float*)d_in[4];
  const float* fc3_w = (const float*)d_in[5];
  const float* g3  = (const float*)d_in[6];
  const float* b3  = (const float*)d_in[7];
  const float* m3  = (const float*)d_in[8];
  const float* v3  = (const float*)d_in[9];
  const float* c1w = (const float*)d_in[10];
  const float* g1  = (const float*)d_in[11];
  const float* b1  = (const float*)d_in[12];
  const float* m1  = (const float*)d_in[13];
  const float* v1  = (const float*)d_in[14];
  const float* c3w = (const float*)d_in[15];
  const float* gk  = (const float*)d_in[16];
  const float* bk  = (const float*)d_in[17];
  const float* mk  = (const float*)d_in[18];
  const float* vk  = (const float*)d_in[19];
  float* out = (float*)d_out;

  float* pooled = (float*)d_ws;          // 32*256 floats
  float* gate   = pooled + 32 * 256;     // 32*256 floats

  pool_kernel<<<8192, 256, 0, stream>>>(x, pooled);
  gate_kernel<<<32, 256, 0, stream>>>(pooled, fc1_w, fc1_b, fc2_w, fc2_b, gate);
  main_kernel<<<2048, 256, 0, stream>>>(x, fc3_w, g3, b3, m3, v3, c1w,
                                        g1, b1, m1, v1, c3w, gk, bk, mk, vk,
                                        gate, out);
}

// Round 3
// 101.549 us; speedup vs baseline: 2.6766x; 2.6766x over previous
//
#include <hip/hip_runtime.h>
#include <math.h>

#define BN_EPS 1e-5f

typedef __attribute__((ext_vector_type(8))) short short8;
typedef __attribute__((ext_vector_type(4))) float f32x4;

__device__ __forceinline__ unsigned short f2bf(float f) {
  union { float f; unsigned u; } c; c.f = f;
  unsigned u = c.u;
  return (unsigned short)((u + 0x7FFFu + ((u >> 16) & 1u)) >> 16);
}
__device__ __forceinline__ float bf2f(unsigned short h) {
  union { unsigned u; float f; } c; c.u = ((unsigned)h) << 16;
  return c.f;
}

// ---------------- Kernel 1: global average pool over H,W ----------------
__global__ __launch_bounds__(256) void pool_kernel(const float* __restrict__ x,
                                                   float* __restrict__ pooled) {
  int bc = blockIdx.x;
  const float4* xp = reinterpret_cast<const float4*>(x + (size_t)bc * 4096);
  int tid = threadIdx.x;
  float s = 0.f;
#pragma unroll
  for (int k = 0; k < 4; ++k) {
    float4 v = xp[k * 256 + tid];
    s += (v.x + v.y) + (v.z + v.w);
  }
#pragma unroll
  for (int m = 32; m >= 1; m >>= 1) s += __shfl_xor(s, m, 64);
  __shared__ float wsum[4];
  if ((tid & 63) == 0) wsum[tid >> 6] = s;
  __syncthreads();
  if (tid == 0) pooled[bc] = (wsum[0] + wsum[1] + wsum[2] + wsum[3]) * (1.f / 4096.f);
}

// ---------------- Kernel 2: gate MLP ----------------
__global__ __launch_bounds__(256) void gate_kernel(const float* __restrict__ pooled,
                                                   const float* __restrict__ fc1_w,
                                                   const float* __restrict__ fc1_b,
                                                   const float* __restrict__ fc2_w,
                                                   const float* __restrict__ fc2_b,
                                                   float* __restrict__ gate) {
  int b = blockIdx.x;
  int tid = threadIdx.x;
  __shared__ float p[256];
  __shared__ float hbuf[64];
  p[tid] = pooled[b * 256 + tid];
  __syncthreads();
  if (tid < 64) {
    float a = fc1_b[tid];
    const float* wr = fc1_w + tid * 256;
#pragma unroll 8
    for (int c = 0; c < 256; ++c) a += p[c] * wr[c];
    hbuf[tid] = fmaxf(a, 0.f);
  }
  __syncthreads();
  float g = fc2_b[tid];
  const float* w2 = fc2_w + tid * 64;
#pragma unroll 8
  for (int j = 0; j < 64; ++j) g += hbuf[j] * w2[j];
  gate[b * 256 + tid] = 1.f / (1.f + expf(-g));
}

// ---------------- Kernel 3: MFMA fc3 + reparam convs + BN + merge + gate
// Grid: (b, hpi, cgh). Wave = s. Lane n = wpi*8+cgL owns one 8x8 tile.
// fc3 via bf16x3 MFMA; epilogue stores DIRECTLY from C-fragments to global.
// Conv results travel via wave-private LDS rows (no cross-wave LDS anywhere).
__global__ __launch_bounds__(256, 2) void main_kernel(
    const float* __restrict__ x, const float* __restrict__ fc3_w,
    const float* __restrict__ g3, const float* __restrict__ b3,
    const float* __restrict__ m3, const float* __restrict__ v3,
    const float* __restrict__ c1w,
    const float* __restrict__ g1, const float* __restrict__ b1,
    const float* __restrict__ m1, const float* __restrict__ v1,
    const float* __restrict__ c3w,
    const float* __restrict__ gk, const float* __restrict__ bk,
    const float* __restrict__ mk, const float* __restrict__ vk,
    const float* __restrict__ gate, float* __restrict__ out) {
  // convbuf: 256 rows x 68 floats (stride-68 pad -> rows spread over banks,
  // 16B-aligned chunks). First 32 KB doubles as the bf16 hi/lo X staging.
  __shared__ float convbuf[256 * 68];
  unsigned short* xs = (unsigned short*)convbuf;  // [s][plane][n][64] chunk-XOR swz

  int bid = blockIdx.x;
  int cgh = bid & 7;
  int hpi = (bid >> 3) & 7;
  int b   = bid >> 6;
  int tid = threadIdx.x;
  int s = __builtin_amdgcn_readfirstlane(tid >> 6);
  int n = tid & 63;            // partition id within shareset (wpi,cgL)
  int r16 = n & 15;            // MFMA row/col within 16-group
  int g   = n >> 4;            // MFMA 4-group (k-group / C-row-group)
  int c_in = (cgh * 8 + (n & 7)) * 4 + s;

  // ---- load this lane's 8x8 tile ----
  float t[64];
  const float* xp = x + (((size_t)b * 256 + c_in) * 64 + (size_t)hpi * 8) * 64 + (n >> 3) * 8;
#pragma unroll
  for (int hh = 0; hh < 8; ++hh) {
    float4 va = *reinterpret_cast<const float4*>(xp + hh * 64);
    float4 vb = *reinterpret_cast<const float4*>(xp + hh * 64 + 4);
    t[hh * 8 + 0] = va.x; t[hh * 8 + 1] = va.y; t[hh * 8 + 2] = va.z; t[hh * 8 + 3] = va.w;
    t[hh * 8 + 4] = vb.x; t[hh * 8 + 5] = vb.y; t[hh * 8 + 6] = vb.z; t[hh * 8 + 7] = vb.w;
  }

  // ---- BN folds (wave-uniform) ----
  float sc3   = g3[s] * rsqrtf(v3[s] + BN_EPS);
  float bias3 = b3[s] - m3[s] * sc3;
  float sc1   = g1[s] * rsqrtf(v1[s] + BN_EPS);
  float bias1 = b1[s] - m1[s] * sc1;
  float sck   = gk[s] * rsqrtf(vk[s] + BN_EPS);
  float biask = bk[s] - mk[s] * sck;
  float cw[9];
#pragma unroll
  for (int d = 0; d < 9; ++d) cw[d] = sck * c3w[s * 9 + d];
  float c0   = sc1 * c1w[s] + cw[4];
  float totb = bias3 + bias1 + biask;

  // ---- stage X as bf16 hi/lo into LDS rows (wave-private), chunk-XOR swz ----
#pragma unroll
  for (int cj = 0; cj < 8; ++cj) {
    int cp = (cj ^ (n & 7)) * 8;
    union { unsigned short u[8]; int4 v; } H, L;
#pragma unroll
    for (int j = 0; j < 8; ++j) {
      float f = t[cj * 8 + j];
      unsigned short hv = f2bf(f);
      H.u[j] = hv;
      L.u[j] = f2bf(f - bf2f(hv));
    }
    *(int4*)&xs[(((s * 2 + 0) * 64) + n) * 64 + cp] = H.v;
    *(int4*)&xs[(((s * 2 + 1) * 64) + n) * 64 + cp] = L.v;
  }

  // ---- A-fragments: sc3*W split to bf16 hi/lo ----
  short8 ahi[2][4], alo[2][4];  // [kt][ot]
  {
    const float* wb = fc3_w + s * 4096;
#pragma unroll
    for (int ot = 0; ot < 4; ++ot)
#pragma unroll
      for (int kt = 0; kt < 2; ++kt) {
        const float* p = wb + (ot * 16 + r16) * 64 + kt * 32 + g * 8;
        float4 w0 = *(const float4*)p;
        float4 w1 = *(const float4*)(p + 4);
        float v[8] = {w0.x, w0.y, w0.z, w0.w, w1.x, w1.y, w1.z, w1.w};
        union { unsigned short u[8]; short8 s8; } H, L;
#pragma unroll
        for (int j = 0; j < 8; ++j) {
          float f = sc3 * v[j];
          unsigned short hv = f2bf(f);
          H.u[j] = hv;
          L.u[j] = f2bf(f - bf2f(hv));
        }
        ahi[kt][ot] = H.s8;
        alo[kt][ot] = L.s8;
      }
  }

  __syncthreads();  // fence: staging (short writes) -> fragment reads

  // ---- MFMA: Y[o][n] accumulation, bf16x3 emulation ----
  f32x4 acc[4][4];
#pragma unroll
  for (int i = 0; i < 4; ++i)
#pragma unroll
    for (int j = 0; j < 4; ++j) acc[i][j] = f32x4{0.f, 0.f, 0.f, 0.f};

#pragma unroll
  for (int nt = 0; nt < 4; ++nt) {
    int nn = nt * 16 + r16;
    short8 bh[2], bl[2];
#pragma unroll
    for (int kt = 0; kt < 2; ++kt) {
      int cp = ((kt * 4 + g) ^ (nn & 7)) * 8;
      bh[kt] = *(const short8*)&xs[(((s * 2 + 0) * 64) + nn) * 64 + cp];
      bl[kt] = *(const short8*)&xs[(((s * 2 + 1) * 64) + nn) * 64 + cp];
    }
#pragma unroll
    for (int ot = 0; ot < 4; ++ot)
#pragma unroll
      for (int kt = 0; kt < 2; ++kt) {
        acc[ot][nt] = __builtin_amdgcn_mfma_f32_16x16x32_bf16(ahi[kt][ot], bh[kt], acc[ot][nt], 0, 0, 0);
        acc[ot][nt] = __builtin_amdgcn_mfma_f32_16x16x32_bf16(ahi[kt][ot], bl[kt], acc[ot][nt], 0, 0, 0);
        acc[ot][nt] = __builtin_amdgcn_mfma_f32_16x16x32_bf16(alo[kt][ot], bh[kt], acc[ot][nt], 0, 0, 0);
      }
  }

  __syncthreads();  // fence: xs reads done before conv floats clobber region

  // ---- conv (+ merged bias) from registers -> LDS row tid, chunk-XOR rot ----
  {
    float* myrow = &convbuf[tid * 68];
    int rot = tid & 15;
#pragma unroll
    for (int hh = 0; hh < 8; ++hh) {
      float cv[8];
#pragma unroll
      for (int ww = 0; ww < 8; ++ww) {
        float v = c0 * t[hh * 8 + ww];
#pragma unroll
        for (int dy = -1; dy <= 1; ++dy)
#pragma unroll
          for (int dx = -1; dx <= 1; ++dx) {
            if (dy == 0 && dx == 0) continue;
            int yy = hh + dy, xx = ww + dx;
            if (yy >= 0 && yy < 8 && xx >= 0 && xx < 8)
              v += cw[(dy + 1) * 3 + (dx + 1)] * t[yy * 8 + xx];
          }
        cv[ww] = v + totb;
      }
      *(f32x4*)&myrow[((hh * 2) ^ rot) * 4]     = f32x4{cv[0], cv[1], cv[2], cv[3]};
      *(f32x4*)&myrow[((hh * 2 + 1) ^ rot) * 4] = f32x4{cv[4], cv[5], cv[6], cv[7]};
    }
  }

  __syncthreads();  // fence: conv writes -> epilogue reads

  // ---- epilogue: direct stores from C-frags ----
  // acc[ot][nt] reg r  ->  o = ot*16 + g*4 + r,  n2 = nt*16 + r16
  // out pixel: channel = hpi*32 + (n2>>3)*4 + s, H = cgh*8 + (o>>3), W = (n2&7)*8 + (o&7)
#pragma unroll
  for (int nt = 0; nt < 4; ++nt) {
    int n2 = nt * 16 + r16;
    int c_out = hpi * 32 + (n2 >> 3) * 4 + s;
    float gmul = gate[b * 256 + c_out];
    int R = s * 64 + n2;  // conv row (written by thread R, same wave)
    const float* crow = &convbuf[R * 68];
    float* outb = out + (((size_t)b * 256 + c_out) * 64 + (size_t)cgh * 8) * 64 + (n2 & 7) * 8;
#pragma unroll
    for (int ot = 0; ot < 4; ++ot) {
      int ch = ot * 4 + g;                       // o-chunk = o/4
      f32x4 cv4 = *(const f32x4*)&crow[(ch ^ (R & 15)) * 4];
      f32x4 a = acc[ot][nt];
      int hh = ot * 2 + (g >> 1);                // o>>3
      int wo = (g & 1) * 4;                      // o&7 base
      float4 o4 = make_float4((a.x + cv4.x) * gmul, (a.y + cv4.y) * gmul,
                              (a.z + cv4.z) * gmul, (a.w + cv4.w) * gmul);
      *(float4*)(outb + hh * 64 + wo) = o4;
    }
  }
}

extern "C" void kernel_launch(void* const* d_in, const int* in_sizes, int n_in,
                              void* d_out, int out_size, void* d_ws, size_t ws_size,
                              hipStream_t stream) {
  const float* x     = (const float*)d_in[0];
  const float* fc1_w = (const float*)d_in[1];
  const float* fc1_b = (const float*)d_in[2];
  const float* fc2_w = (const float*)d_in[3];
  const float* fc2_b = (const float*)d_in[4];
  const float* fc3_w = (const float*)d_in[5];
  const float* g3  = (const float*)d_in[6];
  const float* b3  = (const float*)d_in[7];
  const float* m3  = (const float*)d_in[8];
  const float* v3  = (const float*)d_in[9];
  const float* c1w = (const float*)d_in[10];
  const float* g1  = (const float*)d_in[11];
  const float* b1  = (const float*)d_in[12];
  const float* m1  = (const float*)d_in[13];
  const float* v1  = (const float*)d_in[14];
  const float* c3w = (const float*)d_in[15];
  const float* gk  = (const float*)d_in[16];
  const float* bk  = (const float*)d_in[17];
  const float* mk  = (const float*)d_in[18];
  const float* vk  = (const float*)d_in[19];
  float* out = (float*)d_out;

  float* pooled = (float*)d_ws;
  float* gate   = pooled + 32 * 256;

  pool_kernel<<<8192, 256, 0, stream>>>(x, pooled);
  gate_kernel<<<32, 256, 0, stream>>>(pooled, fc1_w, fc1_b, fc2_w, fc2_b, gate);
  main_kernel<<<2048, 256, 0, stream>>>(x, fc3_w, g3, b3, m3, v3, c1w,
                                        g1, b1, m1, v1, c3w, gk, bk, mk, vk,
                                        gate, out);
}

// Round 5
// 85.061 us; speedup vs baseline: 3.1954x; 1.1938x over previous
//
#include <hip/hip_runtime.h>
#include <hip/hip_bf16.h>
#include <math.h>

#define BN_EPS 1e-5f

typedef __attribute__((ext_vector_type(8))) short short8;
typedef __attribute__((ext_vector_type(4))) float f32x4;

__device__ __forceinline__ unsigned short bfbits(float f) {
  __hip_bfloat16 h = __float2bfloat16(f);           // HW RNE convert
  return *reinterpret_cast<unsigned short*>(&h);
}
__device__ __forceinline__ float bf2f(unsigned short u) {
  union { unsigned v; float f; } c; c.v = ((unsigned)u) << 16;
  return c.f;
}

// ---------------- Kernel 0: prep — A_s = sc3*W_s + C_s, split bf16 hi/lo ----
// 16 blocks: blk -> (s = blk>>2, o-chunk). Thread t -> o = chunk*16 + (t>>4),
// k = (t&15)*4 .. +3. Also writes totb[4].
__global__ __launch_bounds__(256) void prep_kernel(
    const float* __restrict__ fc3_w,
    const float* __restrict__ g3, const float* __restrict__ b3,
    const float* __restrict__ m3, const float* __restrict__ v3,
    const float* __restrict__ c1w,
    const float* __restrict__ g1, const float* __restrict__ b1,
    const float* __restrict__ m1, const float* __restrict__ v1,
    const float* __restrict__ c3w,
    const float* __restrict__ gk, const float* __restrict__ bk,
    const float* __restrict__ mk, const float* __restrict__ vk,
    unsigned short* __restrict__ ahi, unsigned short* __restrict__ alo,
    float* __restrict__ totb) {
  int blk = blockIdx.x;
  int s = blk >> 2;
  int t = threadIdx.x;
  int o = (blk & 3) * 16 + (t >> 4);
  int kc = (t & 15) * 4;
  float sc3 = g3[s] * rsqrtf(v3[s] + BN_EPS);
  float sc1 = g1[s] * rsqrtf(v1[s] + BN_EPS);
  float sck = gk[s] * rsqrtf(vk[s] + BN_EPS);
  float c0 = sc1 * c1w[s] + sck * c3w[s * 9 + 4];
  int oh = o >> 3, ow = o & 7;
  unsigned short H[4], L[4];
#pragma unroll
  for (int j = 0; j < 4; ++j) {
    int k = kc + j;
    int kh = k >> 3, kw = k & 7;
    float a = sc3 * fc3_w[(s * 64 + o) * 64 + k];
    int dy = kh - oh, dx = kw - ow;
    if (dy >= -1 && dy <= 1 && dx >= -1 && dx <= 1)
      a += (dy == 0 && dx == 0) ? c0 : sck * c3w[s * 9 + (dy + 1) * 3 + (dx + 1)];
    unsigned short h = bfbits(a);
    H[j] = h;
    L[j] = bfbits(a - bf2f(h));
  }
  size_t base = (size_t)(s * 64 + o) * 64 + kc;
  *(ushort4*)(ahi + base) = make_ushort4(H[0], H[1], H[2], H[3]);
  *(ushort4*)(alo + base) = make_ushort4(L[0], L[1], L[2], L[3]);
  if (blk == 0 && t < 4) {
    int ss = t;
    float s3 = g3[ss] * rsqrtf(v3[ss] + BN_EPS);
    float s1 = g1[ss] * rsqrtf(v1[ss] + BN_EPS);
    float sk = gk[ss] * rsqrtf(vk[ss] + BN_EPS);
    totb[ss] = (b3[ss] - m3[ss] * s3) + (b1[ss] - m1[ss] * s1) + (bk[ss] - mk[ss] * sk);
  }
}

// ---------------- Kernel 1: global average pool over H,W ----------------
__global__ __launch_bounds__(256) void pool_kernel(const float* __restrict__ x,
                                                   float* __restrict__ pooled) {
  int bc = blockIdx.x;
  const float4* xp = reinterpret_cast<const float4*>(x + (size_t)bc * 4096);
  int tid = threadIdx.x;
  float s = 0.f;
#pragma unroll
  for (int k = 0; k < 4; ++k) {
    float4 v = xp[k * 256 + tid];
    s += (v.x + v.y) + (v.z + v.w);
  }
#pragma unroll
  for (int m = 32; m >= 1; m >>= 1) s += __shfl_xor(s, m, 64);
  __shared__ float wsum[4];
  if ((tid & 63) == 0) wsum[tid >> 6] = s;
  __syncthreads();
  if (tid == 0) pooled[bc] = (wsum[0] + wsum[1] + wsum[2] + wsum[3]) * (1.f / 4096.f);
}

// ---------------- Kernel 2: gate MLP ----------------
__global__ __launch_bounds__(256) void gate_kernel(const float* __restrict__ pooled,
                                                   const float* __restrict__ fc1_w,
                                                   const float* __restrict__ fc1_b,
                                                   const float* __restrict__ fc2_w,
                                                   const float* __restrict__ fc2_b,
                                                   float* __restrict__ gate) {
  int b = blockIdx.x;
  int tid = threadIdx.x;
  __shared__ float p[256];
  __shared__ float hbuf[64];
  p[tid] = pooled[b * 256 + tid];
  __syncthreads();
  if (tid < 64) {
    float a = fc1_b[tid];
    const float* wr = fc1_w + tid * 256;
#pragma unroll 8
    for (int c = 0; c < 256; ++c) a += p[c] * wr[c];
    hbuf[tid] = fmaxf(a, 0.f);
  }
  __syncthreads();
  float g = fc2_b[tid];
  const float* w2 = fc2_w + tid * 64;
#pragma unroll 8
  for (int j = 0; j < 64; ++j) g += hbuf[j] * w2[j];
  gate[b * 256 + tid] = 1.f / (1.f + expf(-g));
}

// ---------------- Kernel 3: main — Y = (A_s @ X + totb) * gate ----------
// Grid (b, hpi, cgh); wave = s; no LDS, no barriers. B-frags loaded directly
// from x (frag k-octet == one pixel row of a tile). A-frags from prep'd ws.
__global__ __launch_bounds__(256, 3) void main_kernel(
    const float* __restrict__ x,
    const unsigned short* __restrict__ ahi, const unsigned short* __restrict__ alo,
    const float* __restrict__ totb, const float* __restrict__ gate,
    float* __restrict__ out) {
  int bid = blockIdx.x;
  int cgh = bid & 7;
  int hpi = (bid >> 3) & 7;
  int b   = bid >> 6;
  int tid = threadIdx.x;
  int s   = __builtin_amdgcn_readfirstlane(tid >> 6);
  int r16 = tid & 15;
  int g   = (tid >> 4) & 3;

  float tb = totb[s];

  // ---- A fragments (bf16 hi/lo, conv folded in) ----
  short8 Ah[2][4], Al[2][4];  // [kt][ot]
#pragma unroll
  for (int ot = 0; ot < 4; ++ot)
#pragma unroll
    for (int kt = 0; kt < 2; ++kt) {
      size_t off = (size_t)(s * 64 + ot * 16 + r16) * 64 + kt * 32 + g * 8;
      Ah[kt][ot] = *(const short8*)(ahi + off);
      Al[kt][ot] = *(const short8*)(alo + off);
    }

  f32x4 acc[4][4];
#pragma unroll
  for (int i = 0; i < 4; ++i)
#pragma unroll
    for (int j = 0; j < 4; ++j) acc[i][j] = f32x4{0.f, 0.f, 0.f, 0.f};

  // ---- B: per (kt,nt) load 8 floats straight from x, cvt, 12 MFMAs ----
#pragma unroll
  for (int kt = 0; kt < 2; ++kt)
#pragma unroll
    for (int nt = 0; nt < 4; ++nt) {
      int n2 = nt * 16 + r16;
      int c_in = (cgh * 8 + (n2 & 7)) * 4 + s;
      const float* bp = x + (size_t)(b * 256 + c_in) * 4096
                        + (hpi * 8 + kt * 4 + g) * 64 + (n2 >> 3) * 8;
      float4 f0 = *(const float4*)bp;
      float4 f1 = *(const float4*)(bp + 4);
      float fv[8] = {f0.x, f0.y, f0.z, f0.w, f1.x, f1.y, f1.z, f1.w};
      union { unsigned short u[8]; short8 v; } BH, BL;
#pragma unroll
      for (int j = 0; j < 8; ++j) {
        unsigned short h = bfbits(fv[j]);
        BH.u[j] = h;
        BL.u[j] = bfbits(fv[j] - bf2f(h));
      }
#pragma unroll
      for (int ot = 0; ot < 4; ++ot) {
        acc[ot][nt] = __builtin_amdgcn_mfma_f32_16x16x32_bf16(Ah[kt][ot], BH.v, acc[ot][nt], 0, 0, 0);
        acc[ot][nt] = __builtin_amdgcn_mfma_f32_16x16x32_bf16(Ah[kt][ot], BL.v, acc[ot][nt], 0, 0, 0);
        acc[ot][nt] = __builtin_amdgcn_mfma_f32_16x16x32_bf16(Al[kt][ot], BH.v, acc[ot][nt], 0, 0, 0);
      }
    }

  // ---- epilogue: direct nontemporal stores from C-frags ----
  // acc[ot][nt] reg r -> o = ot*16 + g*4 + r, col n2 = nt*16 + r16
#pragma unroll
  for (int nt = 0; nt < 4; ++nt) {
    int n2 = nt * 16 + r16;
    int c_out = hpi * 32 + (n2 >> 3) * 4 + s;
    float gmul = gate[b * 256 + c_out];
    float* outb = out + (size_t)(b * 256 + c_out) * 4096 + cgh * 8 * 64 + (n2 & 7) * 8;
#pragma unroll
    for (int ot = 0; ot < 4; ++ot) {
      f32x4 a = acc[ot][nt];
      int hh = ot * 2 + (g >> 1);
      int wo = (g & 1) * 4;
      f32x4 o4 = {(a.x + tb) * gmul, (a.y + tb) * gmul,
                  (a.z + tb) * gmul, (a.w + tb) * gmul};
      __builtin_nontemporal_store(o4, (f32x4*)(outb + hh * 64 + wo));
    }
  }
}

extern "C" void kernel_launch(void* const* d_in, const int* in_sizes, int n_in,
                              void* d_out, int out_size, void* d_ws, size_t ws_size,
                              hipStream_t stream) {
  const float* x     = (const float*)d_in[0];
  const float* fc1_w = (const float*)d_in[1];
  const float* fc1_b = (const float*)d_in[2];
  const float* fc2_w = (const float*)d_in[3];
  const float* fc2_b = (const float*)d_in[4];
  const float* fc3_w = (const float*)d_in[5];
  const float* g3  = (const float*)d_in[6];
  const float* b3  = (const float*)d_in[7];
  const float* m3  = (const float*)d_in[8];
  const float* v3  = (const float*)d_in[9];
  const float* c1w = (const float*)d_in[10];
  const float* g1  = (const float*)d_in[11];
  const float* b1  = (const float*)d_in[12];
  const float* m1  = (const float*)d_in[13];
  const float* v1  = (const float*)d_in[14];
  const float* c3w = (const float*)d_in[15];
  const float* gk  = (const float*)d_in[16];
  const float* bk  = (const float*)d_in[17];
  const float* mk  = (const float*)d_in[18];
  const float* vk  = (const float*)d_in[19];
  float* out = (float*)d_out;

  // ws layout (all 16B-aligned): pooled 32KB | gate 32KB | ahi 32KB | alo 32KB | totb
  float* pooled = (float*)d_ws;
  float* gate   = pooled + 8192;
  unsigned short* ahi = (unsigned short*)(gate + 8192);
  unsigned short* alo = ahi + 16384;
  float* totb   = (float*)(alo + 16384);

  prep_kernel<<<16, 256, 0, stream>>>(fc3_w, g3, b3, m3, v3, c1w,
                                      g1, b1, m1, v1, c3w, gk, bk, mk, vk,
                                      ahi, alo, totb);
  pool_kernel<<<8192, 256, 0, stream>>>(x, pooled);
  gate_kernel<<<32, 256, 0, stream>>>(pooled, fc1_w, fc1_b, fc2_w, fc2_b, gate);
  main_kernel<<<2048, 256, 0, stream>>>(x, ahi, alo, totb, gate, out);
}